// Round 16
// baseline (137.855 us; speedup 1.0000x reference)
//
#include <hip/hip_runtime.h>

#define NB 16
#define C  256
#define H  64
#define W  64
#define E  32
#define F  768
#define HW 4096
#define K5 2048
#define XROWS 4224   // 64 pad + 4096 + 64 pad

typedef __attribute__((ext_vector_type(2))) float f32x2;
typedef __attribute__((ext_vector_type(4))) float f32x4;
typedef __attribute__((ext_vector_type(16))) float f32x16;
typedef __attribute__((ext_vector_type(8))) short s16x8;

__device__ inline unsigned short to_bf16(float f) {
  union { float f; unsigned u; } v; v.f = f;
  unsigned u = v.u;
  u += 0x7fff + ((u >> 16) & 1);
  return (unsigned short)(u >> 16);
}

__device__ inline float from_bf16(unsigned short s) {
  union { unsigned u; float f; } v; v.u = ((unsigned)s) << 16;
  return v.f;
}

__device__ inline void gload16(const void* g, void* l) {
  __builtin_amdgcn_global_load_lds((const __attribute__((address_space(1))) unsigned int*)g,
                                   (__attribute__((address_space(3))) unsigned int*)l, 16, 0, 0);
}

// ---------------------------------------------------------------------------
// k_prep: block [0,384) = p5 transpose->bf16; block [384,640) = p3 pre-pack.
// ---------------------------------------------------------------------------
__global__ __launch_bounds__(256) void k_prep(const float* __restrict__ p5,
                                              unsigned short* __restrict__ p5t,
                                              const float* __restrict__ p3,
                                              float* __restrict__ w3p) {
  const int bid = blockIdx.x;
  const int tid = threadIdx.x;
  if (bid < 384) {
    const int f0 = (bid % 12) * 64;
    const int k0 = (bid / 12) * 64;
    __shared__ __align__(16) unsigned short ls[64][264];
    int fl = tid & 63, k4 = tid >> 6;
    for (int i = 0; i < 16; ++i) {
      int kl = k4 * 16 + i;
      ls[fl][kl] = to_bf16(p5[(size_t)(k0 + kl) * F + f0 + fl]);
    }
    __syncthreads();
#pragma unroll
    for (int j = 0; j < 2; ++j) {
      int chunk = tid + 256 * j;
      int row = chunk >> 3, slot = chunk & 7;
      *(uint4*)(p5t + (size_t)(f0 + row) * K5 + k0 + slot * 8) = *(const uint4*)&ls[row][slot * 8];
    }
  } else {
    const int c = bid - 384;
    if (tid >= 180) return;
    const int i = tid / 20, s = tid % 20;
    const float* wr = p3 + c * 81 + i * 9;
    float v;
    if (s < 10) {
      int q = s >> 1, e = s & 1;
      v = (q < 4) ? wr[2 * q + e] : (e ? 0.f : wr[8]);
    } else {
      int s2 = s - 10, q = s2 >> 1, e = s2 & 1;
      v = (q == 0) ? (e ? wr[0] : 0.f) : wr[2 * (q - 1) + 1 + e];
    }
    w3p[(size_t)(c * 9 + i) * 20 + s] = v;
  }
}

// ---------------------------------------------------------------------------
// k_t13: fused t1 (MFMA) + t3 (9x9 dw, packed f32). One block per (n,c).
// ---------------------------------------------------------------------------
__global__ __launch_bounds__(256) void k_t13(const float* __restrict__ x,
                                             const float* __restrict__ p1,
                                             const float* __restrict__ w3p,
                                             unsigned short* __restrict__ t3g) {
  const int nc = blockIdx.x;
  const int c = nc & 255;
  const int tid = threadIdx.x;
  const int lane = tid & 63;
  const int wv = tid >> 6;

  __shared__ __align__(16) unsigned short xs[64][64];  // 8 KB, swizzled
  __shared__ __align__(16) float t1s[40][76];          // 12.2 KB, zero borders

  for (int i = tid; i < 40 * 76; i += 256) (&t1s[0][0])[i] = 0.f;

  s16x8 afr[2][2];
  {
    const int r = lane & 15;
    const int kb = (lane >> 4) * 8;
#pragma unroll
    for (int m = 0; m < 2; ++m)
#pragma unroll
      for (int kc = 0; kc < 2; ++kc) {
        s16x8 tmp;
#pragma unroll
        for (int j = 0; j < 8; ++j)
          tmp[j] = (short)to_bf16(p1[(kc * 32 + kb + j) * 32 + m * 16 + r]);
        afr[m][kc] = tmp;
      }
  }
  {
    const float* xp = x + (size_t)nc * HW;
#pragma unroll
    for (int t = 0; t < 2; ++t) {
      int uid = tid + 256 * t;
      int h = uid >> 3, uc = uid & 7;
      float4 v0 = *(const float4*)(xp + h * 64 + uc * 8);
      float4 v1 = *(const float4*)(xp + h * 64 + uc * 8 + 4);
      unsigned short b[8] = {to_bf16(v0.x), to_bf16(v0.y), to_bf16(v0.z), to_bf16(v0.w),
                             to_bf16(v1.x), to_bf16(v1.y), to_bf16(v1.z), to_bf16(v1.w)};
      *(uint4*)((char*)&xs[0][0] + h * 128 + ((uc ^ ((h >> 3) & 7)) * 16)) = *(const uint4*)b;
    }
  }
  __syncthreads();
  {
    const int wcol = wv * 16 + (lane & 15);
    f32x4 cf[2] = {{0.f, 0.f, 0.f, 0.f}, {0.f, 0.f, 0.f, 0.f}};
#pragma unroll
    for (int kc = 0; kc < 2; ++kc) {
      const int kb = kc * 32 + (lane >> 4) * 8;
      const char* base = (const char*)&xs[0][0] +
                         kb * 128 + (((wcol >> 3) ^ ((kb >> 3) & 7)) * 16) + (wcol & 7) * 2;
      s16x8 bfrag;
#pragma unroll
      for (int j = 0; j < 8; ++j)
        bfrag[j] = *(const short*)(base + j * 128);
      cf[0] = __builtin_amdgcn_mfma_f32_16x16x32_bf16(afr[0][kc], bfrag, cf[0], 0, 0, 0);
      cf[1] = __builtin_amdgcn_mfma_f32_16x16x32_bf16(afr[1][kc], bfrag, cf[1], 0, 0, 0);
    }
#pragma unroll
    for (int m = 0; m < 2; ++m)
#pragma unroll
      for (int q = 0; q < 4; ++q)
        t1s[4 + m * 16 + (lane >> 4) * 4 + q][4 + wcol] = cf[m][q];
  }
  __syncthreads();
  unsigned short* plane = t3g + (size_t)nc * 2304;  // 36*64
  if (tid < 32) {
    static const int zr[4] = {0, 1, 34, 35};
    int row = zr[tid >> 3], col = (tid & 7) * 8;
    uint4 z = make_uint4(0, 0, 0, 0);
    *(uint4*)(plane + row * 64 + col) = z;
  }
  const int e = tid >> 3, w0 = (tid & 7) * 8;
  f32x2 opk[8] = {};
#pragma unroll
  for (int i = 0; i < 9; ++i) {
    const float* r = &t1s[e + i][w0];
    f32x4 v0 = *(const f32x4*)(r);
    f32x4 v1 = *(const f32x4*)(r + 4);
    f32x4 v2 = *(const f32x4*)(r + 8);
    f32x4 v3 = *(const f32x4*)(r + 12);
    f32x2 wa[8];
    wa[0] = __builtin_shufflevector(v0, v0, 0, 1);
    wa[1] = __builtin_shufflevector(v0, v0, 2, 3);
    wa[2] = __builtin_shufflevector(v1, v1, 0, 1);
    wa[3] = __builtin_shufflevector(v1, v1, 2, 3);
    wa[4] = __builtin_shufflevector(v2, v2, 0, 1);
    wa[5] = __builtin_shufflevector(v2, v2, 2, 3);
    wa[6] = __builtin_shufflevector(v3, v3, 0, 1);
    wa[7] = __builtin_shufflevector(v3, v3, 2, 3);
    const f32x2* wp = (const f32x2*)(w3p + (size_t)(c * 9 + i) * 20);
    f32x2 we0 = wp[0], we1 = wp[1], we2 = wp[2], we3 = wp[3], we4 = wp[4];
    f32x2 wo0 = wp[5], wo1 = wp[6], wo2 = wp[7], wo3 = wp[8], wo4 = wp[9];
#pragma unroll
    for (int t = 0; t < 4; ++t) {
      f32x2 aE = opk[2 * t], aO = opk[2 * t + 1];
      aE += wa[t] * we0;
      aE += wa[t + 1] * we1;
      aE += wa[t + 2] * we2;
      aE += wa[t + 3] * we3;
      aE += wa[t + 4] * we4;
      aO += wa[t] * wo0;
      aO += wa[t + 1] * wo1;
      aO += wa[t + 2] * wo2;
      aO += wa[t + 3] * wo3;
      aO += wa[t + 4] * wo4;
      opk[2 * t] = aE;
      opk[2 * t + 1] = aO;
    }
  }
  unsigned short ob[8];
#pragma unroll
  for (int k = 0; k < 8; ++k) ob[k] = to_bf16(opk[k].x + opk[k].y);
  *(uint4*)(plane + (2 + e) * 64 + w0) = *(const uint4*)ob;
}

// ---------------------------------------------------------------------------
// k_t4kg: (5,1) grouped conv, one block per (n, group of 4 channels).
// Stages the group's 4 contiguous t3 planes (36x64 bf16 each) into LDS via
// global_load_lds with pre-swizzled source slots (sl ^= r&7), computes all 4
// out-channels sharing each LDS read. 1024 blocks.
// ---------------------------------------------------------------------------
__global__ __launch_bounds__(256) void k_t4kg(const unsigned short* __restrict__ t3g,
                                              const float* __restrict__ p4,
                                              unsigned short* __restrict__ t4b) {
  const int blk = blockIdx.x;          // (n, g)
  const int c0 = (blk & 63) * 4;
  const int n = blk >> 6;
  const int tid = threadIdx.x;
  __shared__ __align__(16) unsigned short t3s[4 * 36 * 64];  // 18.4 KB

  const unsigned short* src = t3g + ((size_t)(n * C + c0)) * 2304;
  for (int i = tid; i < 1152; i += 256) {  // 16B chunks: r_full = i>>3, sl = i&7
    int rf = i >> 3, sl = i & 7;
    int sw = sl ^ (rf & 7);
    gload16((const char*)src + rf * 128 + sw * 16, (char*)t3s + i * 16);
  }
  __syncthreads();

  const int e = tid >> 3, w0q = tid & 7;   // slot index
  float acc[4][8];
#pragma unroll
  for (int qo = 0; qo < 4; ++qo)
#pragma unroll
    for (int k = 0; k < 8; ++k) acc[qo][k] = 0.f;
#pragma unroll
  for (int ci = 0; ci < 4; ++ci) {
#pragma unroll
    for (int u = 0; u < 5; ++u) {
      int rf = ci * 36 + e + u;
      uint4 v = *(const uint4*)((const char*)t3s + rf * 128 + ((w0q ^ (rf & 7)) * 16));
      const unsigned short* vs = (const unsigned short*)&v;
      float vf[8];
#pragma unroll
      for (int k = 0; k < 8; ++k) vf[k] = from_bf16(vs[k]);
#pragma unroll
      for (int qo = 0; qo < 4; ++qo) {
        float wv = p4[(c0 + qo) * 20 + ci * 5 + u];
#pragma unroll
        for (int k = 0; k < 8; ++k) acc[qo][k] += vf[k] * wv;
      }
    }
  }
#pragma unroll
  for (int qo = 0; qo < 4; ++qo) {
    unsigned short ob[8];
#pragma unroll
    for (int k = 0; k < 8; ++k) ob[k] = to_bf16(acc[qo][k]);
    *(uint4*)(t4b + ((size_t)(n * C + c0 + qo)) * 2048 + e * 64 + w0q * 8) = *(const uint4*)ob;
  }
}

// ---------------------------------------------------------------------------
// x [n][c][h][w] f32 -> xt [n][64 + h*64+w + 64][c] bf16, zero pads
// ---------------------------------------------------------------------------
__global__ __launch_bounds__(256) void k_xt(const float* __restrict__ x,
                                            unsigned short* __restrict__ xt) {
  const int hi = blockIdx.x;   // 0..65
  const int n = blockIdx.y;
  const int tid = threadIdx.x;
  unsigned short* dst = xt + ((size_t)n * XROWS + hi * 64) * C;
  if (hi == 0 || hi == 65) {
    uint4 z = make_uint4(0, 0, 0, 0);
    uint4* d4 = (uint4*)dst;
#pragma unroll
    for (int i = 0; i < 8; ++i) d4[tid + 256 * i] = z;
    return;
  }
  const int h = hi - 1;
  __shared__ __align__(16) unsigned short ls[64][264];
  const float* xp = x + ((size_t)n * C) * HW + h * 64;
  int w = tid & 63, c4 = tid >> 6;
  for (int i = 0; i < 64; ++i) {
    int c = c4 * 64 + i;
    ls[w][c] = to_bf16(xp[(size_t)c * HW + w]);
  }
  __syncthreads();
#pragma unroll
  for (int j = 0; j < 8; ++j) {
    int chunk = tid + 256 * j;          // 2048 chunks of 16B
    int row = chunk >> 5, slot = chunk & 31;
    *(uint4*)(dst + row * C + slot * 8) = *(const uint4*)&ls[row][slot * 8];
  }
}

// ---------------------------------------------------------------------------
// k_t5m: t5b[4096][768] bf16 = t4b[4096][2048]bf16 x p5t^T.  64x64 tile,
// BK=128, 32x32x16 MFMA, 32 KB LDS, 16-slot XOR swizzle.
// ---------------------------------------------------------------------------
__global__ __launch_bounds__(256) void k_t5m(const unsigned short* __restrict__ A,
                                             const unsigned short* __restrict__ Bt,
                                             unsigned short* __restrict__ Cout) {
  const int bid = blockIdx.x;
  const int wg = (bid & 7) * 96 + (bid >> 3);   // bijective: 768 = 8*96
  const int nt = wg % 12;
  const int mt = wg / 12;
  const int n0 = nt * 64;
  const int m0 = mt * 64;
  const int tid = threadIdx.x;
  const int lane = tid & 63;
  const int wave = tid >> 6;
  const int wm = wave >> 1, wn = wave & 1;
  __shared__ __align__(16) short As[8192];      // 64 x 128 bf16
  __shared__ __align__(16) short Bs[8192];
  f32x16 acc = {};

  for (int k0 = 0; k0 < K5; k0 += 128) {
#pragma unroll
    for (int i = 0; i < 4; ++i) {
      int chunk = i * 256 + tid;       // 0..1023: row r (0..63), slot sl (0..15)
      int r = chunk >> 4, sl = chunk & 15;
      int sw = sl ^ (r & 15);
      gload16((const char*)(A + (size_t)(m0 + r) * K5 + k0) + sw * 16,
              (char*)As + chunk * 16);
      gload16((const char*)(Bt + (size_t)(n0 + r) * K5 + k0) + sw * 16,
              (char*)Bs + chunk * 16);
    }
    __syncthreads();
#pragma unroll
    for (int kq = 0; kq < 8; ++kq) {
      int arow = wm * 32 + (lane & 31);
      int aslot = (kq * 2 + (lane >> 5)) ^ (arow & 15);
      s16x8 af = *(const s16x8*)((const char*)As + arow * 256 + aslot * 16);
      int brow = wn * 32 + (lane & 31);
      int bslot = (kq * 2 + (lane >> 5)) ^ (brow & 15);
      s16x8 bf = *(const s16x8*)((const char*)Bs + brow * 256 + bslot * 16);
      acc = __builtin_amdgcn_mfma_f32_32x32x16_bf16(af, bf, acc, 0, 0, 0);
    }
    __syncthreads();
  }
  const int col = n0 + wn * 32 + (lane & 31);
#pragma unroll
  for (int r = 0; r < 16; ++r) {
    int grow = m0 + wm * 32 + (r & 3) + 8 * (r >> 2) + 4 * (lane >> 5);
    Cout[(size_t)grow * F + col] = to_bf16(acc[r]);
  }
}

// ---------------------------------------------------------------------------
// k_t6: t5b bf16 -> 3-tap dw conv (original f order) -> scale -> bf16, f' order
// ---------------------------------------------------------------------------
__global__ __launch_bounds__(256) void k_t6(const unsigned short* __restrict__ t5b,
                                            const float* __restrict__ p6,
                                            unsigned short* __restrict__ t6b) {
  int idx = blockIdx.x * 256 + threadIdx.x;
  if (idx >= NB * C * F) return;
  int fp = idx % F;
  int nc = idx / F;
  int c = nc & 255;
  int c2 = fp & 255;
  int kk = fp >> 8;
  int f = 3 * c2 + kk;
  const unsigned short* row = t5b + (size_t)nc * F;
  const float* wt = p6 + c * 3;
  float acc = from_bf16(row[f]) * wt[1];
  if (f > 0) acc += from_bf16(row[f - 1]) * wt[0];
  if (f < F - 1) acc += from_bf16(row[f + 1]) * wt[2];
  t6b[idx] = to_bf16(acc * 0.03608439182435161f);
}

// ---------------------------------------------------------------------------
// k_outm: out[n][256][4096] f32 = t6b[n][256][768] x B' (from xt, shifted
// rows). 128x128 tile, 512 thr / 8 waves (2M x 4N, wave-tile 64x32),
// 32x32x16 MFMA, single-buffer 32 KB LDS -> 4 blocks/CU co-resident
// (8 waves/SIMD). Grid 1024 blocks, XCD-swizzled (n slowest).
// ---------------------------------------------------------------------------
__global__ __launch_bounds__(512, 8) void k_outm(const unsigned short* __restrict__ t6b,
                                                 const unsigned short* __restrict__ xt,
                                                 float* __restrict__ outp) {
  const int bid = blockIdx.x;
  const int wg = (bid & 7) * 128 + (bid >> 3);  // bijective: 1024 = 8*128
  const int n  = wg >> 6;                       // 16 n, 64 tiles each
  const int tile = wg & 63;
  const int m0 = (tile >> 5) * 128;             // 2 m-tiles
  const int p0 = (tile & 31) * 128;             // 32 p-tiles
  const int tid = threadIdx.x;
  const int lane = tid & 63;
  const int wid = tid >> 6;                     // 0..7
  const int wm = wid >> 2;                      // 0..1 (64-row half)
  const int wn = wid & 3;                       // 0..3 (32-col quarter)
  __shared__ __align__(16) short As[8192];      // 128x64 bf16 = 16 KB
  __shared__ __align__(16) short Bs[8192];      // 128x64 bf16 = 16 KB
  f32x16 acc[2] = {};
  const unsigned short* Abase = t6b + (size_t)(n * C) * F + m0 * F;
  const unsigned short* Xbase = xt + (size_t)n * XROWS * C;

  for (int kt = 0; kt < 12; ++kt) {
    const int k0 = kt * 64;
    const int kk = k0 >> 8, c20 = k0 & 255;
#pragma unroll
    for (int i = 0; i < 2; ++i) {
      int chunk = i * 512 + tid;
      int r = chunk >> 3, sl = chunk & 7, sw = sl ^ (r & 7);
      gload16((const char*)(Abase + (size_t)r * F + k0) + sw * 16,
              (char*)As + chunk * 16);
      gload16((const char*)(Xbase + (size_t)(p0 + r + (kk << 6)) * C + c20) + sw * 16,
              (char*)Bs + chunk * 16);
    }
    __syncthreads();
#pragma unroll
    for (int kq = 0; kq < 4; ++kq) {
      s16x8 af[2], bf;
#pragma unroll
      for (int mi = 0; mi < 2; ++mi) {
        int row = wm * 64 + mi * 32 + (lane & 31);
        int byte = (row * 128 + kq * 32 + ((lane >> 5) * 16)) ^ ((row & 7) << 4);
        af[mi] = *(const s16x8*)((const char*)As + byte);
      }
      {
        int row = wn * 32 + (lane & 31);
        int byte = (row * 128 + kq * 32 + ((lane >> 5) * 16)) ^ ((row & 7) << 4);
        bf = *(const s16x8*)((const char*)Bs + byte);
      }
#pragma unroll
      for (int mi = 0; mi < 2; ++mi)
        acc[mi] = __builtin_amdgcn_mfma_f32_32x32x16_bf16(af[mi], bf, acc[mi], 0, 0, 0);
    }
    __syncthreads();
  }
  float* obase = outp + ((size_t)(n * C) + m0) * HW;
  const int gcol = p0 + wn * 32 + (lane & 31);
#pragma unroll
  for (int mi = 0; mi < 2; ++mi) {
#pragma unroll
    for (int r = 0; r < 16; ++r) {
      int grow = wm * 64 + mi * 32 + (r & 3) + 8 * (r >> 2) + 4 * (lane >> 5);
      obase[(size_t)grow * HW + gcol] = acc[mi][r];
    }
  }
}

extern "C" void kernel_launch(void* const* d_in, const int* in_sizes, int n_in,
                              void* d_out, int out_size, void* d_ws, size_t ws_size,
                              hipStream_t stream) {
  (void)in_sizes; (void)n_in; (void)out_size; (void)ws_size;
  const float* x  = (const float*)d_in[0];
  const float* p1 = (const float*)d_in[1];
  const float* p3 = (const float*)d_in[2];
  const float* p4 = (const float*)d_in[3];
  const float* p5 = (const float*)d_in[4];
  const float* p6 = (const float*)d_in[5];
  float* out = (float*)d_out;

  char* ws = (char*)d_ws;
  // Lifetime-overlaid workspace:
  //  [0      , 18.87M): t3g  (k_t13 -> k_t4kg); then t6b at [0, 6.29M) and
  //                      xt at [6.29M, 40.89M) (k_xt -> k_outm)
  //  [18.87M , 35.65M): t4b  (k_t4kg -> k_t5m)
  //  [35.65M , 38.80M): p5t  (k_prep -> k_t5m)
  //  [38.80M , 45.10M): t5b bf16 (k_t5m -> k_t6)
  //  [45.10M+,       ): w3p (k_prep -> k_t13)
  unsigned short* t3g = (unsigned short*)ws;
  unsigned short* t4b = (unsigned short*)(ws + 18874368);
  unsigned short* p5t = (unsigned short*)(ws + 35651584);
  unsigned short* t5b = (unsigned short*)(ws + 38797312);
  float*          w3p = (float*)(ws + 47290368);
  unsigned short* t6b = (unsigned short*)ws;
  unsigned short* xt  = (unsigned short*)(ws + 6291456);

  k_prep<<<dim3(640), 256, 0, stream>>>(p5, p5t, p3, w3p);
  k_t13 <<<dim3(NB * C), 256, 0, stream>>>(x, p1, w3p, t3g);
  k_t4kg<<<dim3(NB * 64), 256, 0, stream>>>(t3g, p4, t4b);
  k_t5m <<<dim3(768), 256, 0, stream>>>(t4b, p5t, t5b);
  k_t6  <<<dim3((NB * C * F + 255) / 256), 256, 0, stream>>>(t5b, p6, t6b);
  k_xt  <<<dim3(66, NB), 256, 0, stream>>>(x, xt);
  k_outm<<<dim3(1024), 512, 0, stream>>>(t6b, xt, out);
}

// Round 17
// 121.476 us; speedup vs baseline: 1.1348x; 1.1348x over previous
//
#include <hip/hip_runtime.h>

#define NB 16
#define C  256
#define H  64
#define W  64
#define E  32
#define F  768
#define HW 4096
#define K5 2048
#define XROWS 4224   // 64 pad + 4096 + 64 pad

typedef __attribute__((ext_vector_type(2))) float f32x2;
typedef __attribute__((ext_vector_type(4))) float f32x4;
typedef __attribute__((ext_vector_type(16))) float f32x16;
typedef __attribute__((ext_vector_type(8))) short s16x8;

__device__ inline unsigned short to_bf16(float f) {
  union { float f; unsigned u; } v; v.f = f;
  unsigned u = v.u;
  u += 0x7fff + ((u >> 16) & 1);
  return (unsigned short)(u >> 16);
}

__device__ inline float from_bf16(unsigned short s) {
  union { unsigned u; float f; } v; v.u = ((unsigned)s) << 16;
  return v.f;
}

__device__ inline void gload16(const void* g, void* l) {
  __builtin_amdgcn_global_load_lds((const __attribute__((address_space(1))) unsigned int*)g,
                                   (__attribute__((address_space(3))) unsigned int*)l, 16, 0, 0);
}

// ---------------------------------------------------------------------------
// k_prep: block [0,384) = p5 transpose->bf16; block [384,640) = p3 pre-pack.
// ---------------------------------------------------------------------------
__global__ __launch_bounds__(256) void k_prep(const float* __restrict__ p5,
                                              unsigned short* __restrict__ p5t,
                                              const float* __restrict__ p3,
                                              float* __restrict__ w3p) {
  const int bid = blockIdx.x;
  const int tid = threadIdx.x;
  if (bid < 384) {
    const int f0 = (bid % 12) * 64;
    const int k0 = (bid / 12) * 64;
    __shared__ __align__(16) unsigned short ls[64][264];
    int fl = tid & 63, k4 = tid >> 6;
    for (int i = 0; i < 16; ++i) {
      int kl = k4 * 16 + i;
      ls[fl][kl] = to_bf16(p5[(size_t)(k0 + kl) * F + f0 + fl]);
    }
    __syncthreads();
#pragma unroll
    for (int j = 0; j < 2; ++j) {
      int chunk = tid + 256 * j;
      int row = chunk >> 3, slot = chunk & 7;
      *(uint4*)(p5t + (size_t)(f0 + row) * K5 + k0 + slot * 8) = *(const uint4*)&ls[row][slot * 8];
    }
  } else {
    const int c = bid - 384;
    if (tid >= 180) return;
    const int i = tid / 20, s = tid % 20;
    const float* wr = p3 + c * 81 + i * 9;
    float v;
    if (s < 10) {
      int q = s >> 1, e = s & 1;
      v = (q < 4) ? wr[2 * q + e] : (e ? 0.f : wr[8]);
    } else {
      int s2 = s - 10, q = s2 >> 1, e = s2 & 1;
      v = (q == 0) ? (e ? wr[0] : 0.f) : wr[2 * (q - 1) + 1 + e];
    }
    w3p[(size_t)(c * 9 + i) * 20 + s] = v;
  }
}

// ---------------------------------------------------------------------------
// k_t13: fused t1 (MFMA) + t3 (9x9 dw, packed f32). One block per (n,c).
// ---------------------------------------------------------------------------
__global__ __launch_bounds__(256) void k_t13(const float* __restrict__ x,
                                             const float* __restrict__ p1,
                                             const float* __restrict__ w3p,
                                             unsigned short* __restrict__ t3g) {
  const int nc = blockIdx.x;
  const int c = nc & 255;
  const int tid = threadIdx.x;
  const int lane = tid & 63;
  const int wv = tid >> 6;

  __shared__ __align__(16) unsigned short xs[64][64];  // 8 KB, swizzled
  __shared__ __align__(16) float t1s[40][76];          // 12.2 KB, zero borders

  for (int i = tid; i < 40 * 76; i += 256) (&t1s[0][0])[i] = 0.f;

  s16x8 afr[2][2];
  {
    const int r = lane & 15;
    const int kb = (lane >> 4) * 8;
#pragma unroll
    for (int m = 0; m < 2; ++m)
#pragma unroll
      for (int kc = 0; kc < 2; ++kc) {
        s16x8 tmp;
#pragma unroll
        for (int j = 0; j < 8; ++j)
          tmp[j] = (short)to_bf16(p1[(kc * 32 + kb + j) * 32 + m * 16 + r]);
        afr[m][kc] = tmp;
      }
  }
  {
    const float* xp = x + (size_t)nc * HW;
#pragma unroll
    for (int t = 0; t < 2; ++t) {
      int uid = tid + 256 * t;
      int h = uid >> 3, uc = uid & 7;
      float4 v0 = *(const float4*)(xp + h * 64 + uc * 8);
      float4 v1 = *(const float4*)(xp + h * 64 + uc * 8 + 4);
      unsigned short b[8] = {to_bf16(v0.x), to_bf16(v0.y), to_bf16(v0.z), to_bf16(v0.w),
                             to_bf16(v1.x), to_bf16(v1.y), to_bf16(v1.z), to_bf16(v1.w)};
      *(uint4*)((char*)&xs[0][0] + h * 128 + ((uc ^ ((h >> 3) & 7)) * 16)) = *(const uint4*)b;
    }
  }
  __syncthreads();
  {
    const int wcol = wv * 16 + (lane & 15);
    f32x4 cf[2] = {{0.f, 0.f, 0.f, 0.f}, {0.f, 0.f, 0.f, 0.f}};
#pragma unroll
    for (int kc = 0; kc < 2; ++kc) {
      const int kb = kc * 32 + (lane >> 4) * 8;
      const char* base = (const char*)&xs[0][0] +
                         kb * 128 + (((wcol >> 3) ^ ((kb >> 3) & 7)) * 16) + (wcol & 7) * 2;
      s16x8 bfrag;
#pragma unroll
      for (int j = 0; j < 8; ++j)
        bfrag[j] = *(const short*)(base + j * 128);
      cf[0] = __builtin_amdgcn_mfma_f32_16x16x32_bf16(afr[0][kc], bfrag, cf[0], 0, 0, 0);
      cf[1] = __builtin_amdgcn_mfma_f32_16x16x32_bf16(afr[1][kc], bfrag, cf[1], 0, 0, 0);
    }
#pragma unroll
    for (int m = 0; m < 2; ++m)
#pragma unroll
      for (int q = 0; q < 4; ++q)
        t1s[4 + m * 16 + (lane >> 4) * 4 + q][4 + wcol] = cf[m][q];
  }
  __syncthreads();
  unsigned short* plane = t3g + (size_t)nc * 2304;  // 36*64
  if (tid < 32) {
    static const int zr[4] = {0, 1, 34, 35};
    int row = zr[tid >> 3], col = (tid & 7) * 8;
    uint4 z = make_uint4(0, 0, 0, 0);
    *(uint4*)(plane + row * 64 + col) = z;
  }
  const int e = tid >> 3, w0 = (tid & 7) * 8;
  f32x2 opk[8] = {};
#pragma unroll
  for (int i = 0; i < 9; ++i) {
    const float* r = &t1s[e + i][w0];
    f32x4 v0 = *(const f32x4*)(r);
    f32x4 v1 = *(const f32x4*)(r + 4);
    f32x4 v2 = *(const f32x4*)(r + 8);
    f32x4 v3 = *(const f32x4*)(r + 12);
    f32x2 wa[8];
    wa[0] = __builtin_shufflevector(v0, v0, 0, 1);
    wa[1] = __builtin_shufflevector(v0, v0, 2, 3);
    wa[2] = __builtin_shufflevector(v1, v1, 0, 1);
    wa[3] = __builtin_shufflevector(v1, v1, 2, 3);
    wa[4] = __builtin_shufflevector(v2, v2, 0, 1);
    wa[5] = __builtin_shufflevector(v2, v2, 2, 3);
    wa[6] = __builtin_shufflevector(v3, v3, 0, 1);
    wa[7] = __builtin_shufflevector(v3, v3, 2, 3);
    const f32x2* wp = (const f32x2*)(w3p + (size_t)(c * 9 + i) * 20);
    f32x2 we0 = wp[0], we1 = wp[1], we2 = wp[2], we3 = wp[3], we4 = wp[4];
    f32x2 wo0 = wp[5], wo1 = wp[6], wo2 = wp[7], wo3 = wp[8], wo4 = wp[9];
#pragma unroll
    for (int t = 0; t < 4; ++t) {
      f32x2 aE = opk[2 * t], aO = opk[2 * t + 1];
      aE += wa[t] * we0;
      aE += wa[t + 1] * we1;
      aE += wa[t + 2] * we2;
      aE += wa[t + 3] * we3;
      aE += wa[t + 4] * we4;
      aO += wa[t] * wo0;
      aO += wa[t + 1] * wo1;
      aO += wa[t + 2] * wo2;
      aO += wa[t + 3] * wo3;
      aO += wa[t + 4] * wo4;
      opk[2 * t] = aE;
      opk[2 * t + 1] = aO;
    }
  }
  unsigned short ob[8];
#pragma unroll
  for (int k = 0; k < 8; ++k) ob[k] = to_bf16(opk[k].x + opk[k].y);
  *(uint4*)(plane + (2 + e) * 64 + w0) = *(const uint4*)ob;
}

// ---------------------------------------------------------------------------
// k_t4kg: (5,1) grouped conv, one block per (n, group of 4 channels).
// ---------------------------------------------------------------------------
__global__ __launch_bounds__(256) void k_t4kg(const unsigned short* __restrict__ t3g,
                                              const float* __restrict__ p4,
                                              unsigned short* __restrict__ t4b) {
  const int blk = blockIdx.x;          // (n, g)
  const int c0 = (blk & 63) * 4;
  const int n = blk >> 6;
  const int tid = threadIdx.x;
  __shared__ __align__(16) unsigned short t3s[4 * 36 * 64];  // 18.4 KB

  const unsigned short* src = t3g + ((size_t)(n * C + c0)) * 2304;
  for (int i = tid; i < 1152; i += 256) {  // 16B chunks: r_full = i>>3, sl = i&7
    int rf = i >> 3, sl = i & 7;
    int sw = sl ^ (rf & 7);
    gload16((const char*)src + rf * 128 + sw * 16, (char*)t3s + i * 16);
  }
  __syncthreads();

  const int e = tid >> 3, w0q = tid & 7;   // slot index
  float acc[4][8];
#pragma unroll
  for (int qo = 0; qo < 4; ++qo)
#pragma unroll
    for (int k = 0; k < 8; ++k) acc[qo][k] = 0.f;
#pragma unroll
  for (int ci = 0; ci < 4; ++ci) {
#pragma unroll
    for (int u = 0; u < 5; ++u) {
      int rf = ci * 36 + e + u;
      uint4 v = *(const uint4*)((const char*)t3s + rf * 128 + ((w0q ^ (rf & 7)) * 16));
      const unsigned short* vs = (const unsigned short*)&v;
      float vf[8];
#pragma unroll
      for (int k = 0; k < 8; ++k) vf[k] = from_bf16(vs[k]);
#pragma unroll
      for (int qo = 0; qo < 4; ++qo) {
        float wv = p4[(c0 + qo) * 20 + ci * 5 + u];
#pragma unroll
        for (int k = 0; k < 8; ++k) acc[qo][k] += vf[k] * wv;
      }
    }
  }
#pragma unroll
  for (int qo = 0; qo < 4; ++qo) {
    unsigned short ob[8];
#pragma unroll
    for (int k = 0; k < 8; ++k) ob[k] = to_bf16(acc[qo][k]);
    *(uint4*)(t4b + ((size_t)(n * C + c0 + qo)) * 2048 + e * 64 + w0q * 8) = *(const uint4*)ob;
  }
}

// ---------------------------------------------------------------------------
// x [n][c][h][w] f32 -> xt [n][64 + h*64+w + 64][c] bf16, zero pads
// ---------------------------------------------------------------------------
__global__ __launch_bounds__(256) void k_xt(const float* __restrict__ x,
                                            unsigned short* __restrict__ xt) {
  const int hi = blockIdx.x;   // 0..65
  const int n = blockIdx.y;
  const int tid = threadIdx.x;
  unsigned short* dst = xt + ((size_t)n * XROWS + hi * 64) * C;
  if (hi == 0 || hi == 65) {
    uint4 z = make_uint4(0, 0, 0, 0);
    uint4* d4 = (uint4*)dst;
#pragma unroll
    for (int i = 0; i < 8; ++i) d4[tid + 256 * i] = z;
    return;
  }
  const int h = hi - 1;
  __shared__ __align__(16) unsigned short ls[64][264];
  const float* xp = x + ((size_t)n * C) * HW + h * 64;
  int w = tid & 63, c4 = tid >> 6;
  for (int i = 0; i < 64; ++i) {
    int c = c4 * 64 + i;
    ls[w][c] = to_bf16(xp[(size_t)c * HW + w]);
  }
  __syncthreads();
#pragma unroll
  for (int j = 0; j < 8; ++j) {
    int chunk = tid + 256 * j;          // 2048 chunks of 16B
    int row = chunk >> 5, slot = chunk & 31;
    *(uint4*)(dst + row * C + slot * 8) = *(const uint4*)&ls[row][slot * 8];
  }
}

// ---------------------------------------------------------------------------
// k_t5m: t5b[4096][768] bf16 = t4b[4096][2048]bf16 x p5t^T.  64x64 tile,
// BK=128, 32x32x16 MFMA, 32 KB LDS, 16-slot XOR swizzle.
// ---------------------------------------------------------------------------
__global__ __launch_bounds__(256) void k_t5m(const unsigned short* __restrict__ A,
                                             const unsigned short* __restrict__ Bt,
                                             unsigned short* __restrict__ Cout) {
  const int bid = blockIdx.x;
  const int wg = (bid & 7) * 96 + (bid >> 3);   // bijective: 768 = 8*96
  const int nt = wg % 12;
  const int mt = wg / 12;
  const int n0 = nt * 64;
  const int m0 = mt * 64;
  const int tid = threadIdx.x;
  const int lane = tid & 63;
  const int wave = tid >> 6;
  const int wm = wave >> 1, wn = wave & 1;
  __shared__ __align__(16) short As[8192];      // 64 x 128 bf16
  __shared__ __align__(16) short Bs[8192];
  f32x16 acc = {};

  for (int k0 = 0; k0 < K5; k0 += 128) {
#pragma unroll
    for (int i = 0; i < 4; ++i) {
      int chunk = i * 256 + tid;       // 0..1023: row r (0..63), slot sl (0..15)
      int r = chunk >> 4, sl = chunk & 15;
      int sw = sl ^ (r & 15);
      gload16((const char*)(A + (size_t)(m0 + r) * K5 + k0) + sw * 16,
              (char*)As + chunk * 16);
      gload16((const char*)(Bt + (size_t)(n0 + r) * K5 + k0) + sw * 16,
              (char*)Bs + chunk * 16);
    }
    __syncthreads();
#pragma unroll
    for (int kq = 0; kq < 8; ++kq) {
      int arow = wm * 32 + (lane & 31);
      int aslot = (kq * 2 + (lane >> 5)) ^ (arow & 15);
      s16x8 af = *(const s16x8*)((const char*)As + arow * 256 + aslot * 16);
      int brow = wn * 32 + (lane & 31);
      int bslot = (kq * 2 + (lane >> 5)) ^ (brow & 15);
      s16x8 bf = *(const s16x8*)((const char*)Bs + brow * 256 + bslot * 16);
      acc = __builtin_amdgcn_mfma_f32_32x32x16_bf16(af, bf, acc, 0, 0, 0);
    }
    __syncthreads();
  }
  const int col = n0 + wn * 32 + (lane & 31);
#pragma unroll
  for (int r = 0; r < 16; ++r) {
    int grow = m0 + wm * 32 + (r & 3) + 8 * (r >> 2) + 4 * (lane >> 5);
    Cout[(size_t)grow * F + col] = to_bf16(acc[r]);
  }
}

// ---------------------------------------------------------------------------
// k_t6: t5b bf16 -> 3-tap dw conv (original f order) -> scale -> bf16, f' order
// ---------------------------------------------------------------------------
__global__ __launch_bounds__(256) void k_t6(const unsigned short* __restrict__ t5b,
                                            const float* __restrict__ p6,
                                            unsigned short* __restrict__ t6b) {
  int idx = blockIdx.x * 256 + threadIdx.x;
  if (idx >= NB * C * F) return;
  int fp = idx % F;
  int nc = idx / F;
  int c = nc & 255;
  int c2 = fp & 255;
  int kk = fp >> 8;
  int f = 3 * c2 + kk;
  const unsigned short* row = t5b + (size_t)nc * F;
  const float* wt = p6 + c * 3;
  float acc = from_bf16(row[f]) * wt[1];
  if (f > 0) acc += from_bf16(row[f - 1]) * wt[0];
  if (f < F - 1) acc += from_bf16(row[f + 1]) * wt[2];
  t6b[idx] = to_bf16(acc * 0.03608439182435161f);
}

// ---------------------------------------------------------------------------
// k_outm: out[n][256][4096] f32 = t6b[n][256][768] x B' (from xt, shifted
// rows). 128x256 tile, 512 thr / 8 waves (2M x 4N, wave-tile 64x64),
// 32x32x16 MFMA, single-buffer 48 KB LDS -> 2 blocks/CU co-resident.
// (r13 configuration: measured 41.8 us, minimal HBM traffic.)
// ---------------------------------------------------------------------------
__global__ __launch_bounds__(512, 4) void k_outm(const unsigned short* __restrict__ t6b,
                                                 const unsigned short* __restrict__ xt,
                                                 float* __restrict__ outp) {
  const int bid = blockIdx.x;
  const int wg = (bid & 7) * 64 + (bid >> 3);   // bijective: 512 = 8*64
  const int n  = wg >> 5;                       // 16 n, 32 tiles each
  const int tile = wg & 31;
  const int p0 = (tile & 15) * 256;             // 16 p-tiles
  const int m0 = (tile >> 4) * 128;             // 2 m-tiles
  const int tid = threadIdx.x;
  const int lane = tid & 63;
  const int wid = tid >> 6;                     // 0..7
  const int wm = wid >> 2;                      // 0..1
  const int wn = wid & 3;                       // 0..3
  __shared__ __align__(16) short As[8192];      // 128x64 bf16 = 16 KB
  __shared__ __align__(16) short Bs[16384];     // 256x64 bf16 = 32 KB
  f32x16 acc[2][2] = {};
  const unsigned short* Abase = t6b + (size_t)(n * C) * F + m0 * F;
  const unsigned short* Xbase = xt + (size_t)n * XROWS * C;

  for (int kt = 0; kt < 12; ++kt) {
    const int k0 = kt * 64;
    const int kk = k0 >> 8, c20 = k0 & 255;
#pragma unroll
    for (int i = 0; i < 2; ++i) {
      int chunk = i * 512 + tid;
      int r = chunk >> 3, sl = chunk & 7, sw = sl ^ (r & 7);
      gload16((const char*)(Abase + (size_t)r * F + k0) + sw * 16,
              (char*)As + chunk * 16);
    }
#pragma unroll
    for (int i = 0; i < 4; ++i) {
      int chunk = i * 512 + tid;
      int r = chunk >> 3, sl = chunk & 7, sw = sl ^ (r & 7);
      gload16((const char*)(Xbase + (size_t)(p0 + r + (kk << 6)) * C + c20) + sw * 16,
              (char*)Bs + chunk * 16);
    }
    __syncthreads();
#pragma unroll
    for (int kq = 0; kq < 4; ++kq) {
      s16x8 af[2], bf[2];
#pragma unroll
      for (int mi = 0; mi < 2; ++mi) {
        int row = wm * 64 + mi * 32 + (lane & 31);
        int byte = (row * 128 + kq * 32 + ((lane >> 5) * 16)) ^ ((row & 7) << 4);
        af[mi] = *(const s16x8*)((const char*)As + byte);
      }
#pragma unroll
      for (int ni = 0; ni < 2; ++ni) {
        int row = wn * 64 + ni * 32 + (lane & 31);
        int byte = (row * 128 + kq * 32 + ((lane >> 5) * 16)) ^ ((row & 7) << 4);
        bf[ni] = *(const s16x8*)((const char*)Bs + byte);
      }
#pragma unroll
      for (int mi = 0; mi < 2; ++mi)
#pragma unroll
        for (int ni = 0; ni < 2; ++ni)
          acc[mi][ni] = __builtin_amdgcn_mfma_f32_32x32x16_bf16(af[mi], bf[ni], acc[mi][ni], 0, 0, 0);
    }
    __syncthreads();
  }
  float* obase = outp + ((size_t)(n * C) + m0) * HW;
#pragma unroll
  for (int mi = 0; mi < 2; ++mi) {
#pragma unroll
    for (int ni = 0; ni < 2; ++ni) {
      int gcol = p0 + wn * 64 + ni * 32 + (lane & 31);
#pragma unroll
      for (int r = 0; r < 16; ++r) {
        int grow = wm * 64 + mi * 32 + (r & 3) + 8 * (r >> 2) + 4 * (lane >> 5);
        obase[(size_t)grow * HW + gcol] = acc[mi][ni][r];
      }
    }
  }
}

extern "C" void kernel_launch(void* const* d_in, const int* in_sizes, int n_in,
                              void* d_out, int out_size, void* d_ws, size_t ws_size,
                              hipStream_t stream) {
  (void)in_sizes; (void)n_in; (void)out_size; (void)ws_size;
  const float* x  = (const float*)d_in[0];
  const float* p1 = (const float*)d_in[1];
  const float* p3 = (const float*)d_in[2];
  const float* p4 = (const float*)d_in[3];
  const float* p5 = (const float*)d_in[4];
  const float* p6 = (const float*)d_in[5];
  float* out = (float*)d_out;

  char* ws = (char*)d_ws;
  // Lifetime-overlaid workspace:
  //  [0      , 18.87M): t3g  (k_t13 -> k_t4kg); then t6b at [0, 6.29M) and
  //                      xt at [6.29M, 40.89M) (k_xt -> k_outm)
  //  [18.87M , 35.65M): t4b  (k_t4kg -> k_t5m)
  //  [35.65M , 38.80M): p5t  (k_prep -> k_t5m)
  //  [38.80M , 45.10M): t5b bf16 (k_t5m -> k_t6)
  //  [45.10M+,       ): w3p (k_prep -> k_t13)
  unsigned short* t3g = (unsigned short*)ws;
  unsigned short* t4b = (unsigned short*)(ws + 18874368);
  unsigned short* p5t = (unsigned short*)(ws + 35651584);
  unsigned short* t5b = (unsigned short*)(ws + 38797312);
  float*          w3p = (float*)(ws + 47290368);
  unsigned short* t6b = (unsigned short*)ws;
  unsigned short* xt  = (unsigned short*)(ws + 6291456);

  k_prep<<<dim3(640), 256, 0, stream>>>(p5, p5t, p3, w3p);
  k_t13 <<<dim3(NB * C), 256, 0, stream>>>(x, p1, w3p, t3g);
  k_t4kg<<<dim3(NB * 64), 256, 0, stream>>>(t3g, p4, t4b);
  k_t5m <<<dim3(768), 256, 0, stream>>>(t4b, p5t, t5b);
  k_t6  <<<dim3((NB * C * F + 255) / 256), 256, 0, stream>>>(t5b, p6, t6b);
  k_xt  <<<dim3(66, NB), 256, 0, stream>>>(x, xt);
  k_outm<<<dim3(512), 512, 0, stream>>>(t6b, xt, out);
}